// Round 10
// baseline (186.392 us; speedup 1.0000x reference)
//
#include <hip/hip_runtime.h>

// DTYPES SETTLED (R6 post-mortem, executed-path evidence; R7/R8/R9 passed on it):
//   boxes = fp32 (float*), mask = int32 (int*), out = fp32 (float*).
//
// GROUND TRUTH (R9 post-mortem): timed bench = 33.9us for main+finalize+launches;
// profiled 52us is rocprof-inflated. Main loop moves 167.8 MB in ~29us = ~5.8 TB/s
// = ~92% of the 6.3 TB/s copy ceiling -> main loop is at the memory roofline.
// R10: single change vs R7 — fuse the reduction (deterministic fixed-point u64
// atomics + ticket) to delete the finalize launch. LDS staging reverted (R9: -1.1us).

constexpr float  EPSF      = 1e-9f;
constexpr float  HALF_PI_F = 1.5707963267948966f;
constexpr float  INV_PI2_4 = 0.40528473456935109f;   // 4 / pi^2
constexpr double FIXSCALE  = 33554432.0;             // 2^25 fixed-point scale

__device__ __forceinline__ float fast_rcp(float x) { return __builtin_amdgcn_rcpf(x); }

// minimax atan on [0,1], extended by atan(x) = pi/2 - atan(1/x); max err ~1e-6
// (validated within harness threshold by R1/R2/R4/R7/R8/R9 passes)
__device__ __forceinline__ float fast_atan(float t) {
    float a = fabsf(t);
    bool big = a > 1.0f;
    float x = big ? fast_rcp(a) : a;
    float s = x * x;
    float p = -0.0117212f;
    p = fmaf(p, s, 0.05265332f);
    p = fmaf(p, s, -0.11643287f);
    p = fmaf(p, s, 0.19354346f);
    p = fmaf(p, s, -0.33262347f);
    p = fmaf(p, s, 0.99997726f);
    p = x * p;
    float r = big ? (HALF_PI_F - p) : p;
    return copysignf(r, t);
}

__device__ __forceinline__ float ciou_one(float x1a, float y1a, float x2a, float y2a,
                                          float x1b, float y1b, float x2b, float y2b) {
    float xmin = fmaxf(x1a, x1b), ymin = fmaxf(y1a, y1b);
    float xmax = fminf(x2a, x2b), ymax = fminf(y2a, y2b);
    float inter = fmaxf(xmax - xmin, 0.0f) * fmaxf(ymax - ymin, 0.0f);
    float wa = x2a - x1a, ha = y2a - y1a;
    float wb = x2b - x1b, hb = y2b - y1b;
    float uni = wa * ha + wb * hb - inter;
    float iou = inter * fast_rcp(uni + EPSF);
    float dx = (x1a + x2a) - (x1b + x2b);
    float dy = (y1a + y2a) - (y1b + y2b);
    float cd = 0.25f * (dx * dx + dy * dy);
    float cw = fmaxf(x2a, x2b) - fminf(x1a, x1b);
    float ch = fmaxf(y2a, y2b) - fminf(y1a, y1b);
    float diag = cw * cw + ch * ch + EPSF;
    // atan(wa/ha') - atan(wb/hb') == atan((wa*hb' - wb*ha')/(ha'*hb' + wa*wb));
    // both ratios >= 0, so branch-free exact, result in (-pi/2, pi/2)
    float ha_ = ha + EPSF, hb_ = hb + EPSF;
    float at = fast_atan((wa * hb_ - wb * ha_) * fast_rcp(ha_ * hb_ + wa * wb + EPSF));
    float v = INV_PI2_4 * at * at;
    float av = v * v * fast_rcp(v - iou + 1.0f + EPSF);   // alpha * v
    return iou - cd * fast_rcp(diag) - av;
}

// Main (R7 body, proven 33.87us): 1024-box tile; thread i owns boxes base+i+256k.
// Fused reduction: block partial -> u64 fixed-point atomics (order-independent,
// deterministic); ticket winner computes out[0].
// acc[0]=loss*2^25, acc[1]=count, acc[2]=ticket. Zeroed by memset node each call.
__global__ __launch_bounds__(256) void ciou_main(const float4* __restrict__ pred4,
                                                 const float4* __restrict__ targ4,
                                                 const int* __restrict__ mask,
                                                 float* __restrict__ out, int n,
                                                 unsigned long long* __restrict__ acc) {
    const int i = threadIdx.x;
    float lsum = 0.0f;
    int cnt = 0;

    for (int base = blockIdx.x * 1024; base < n; base += gridDim.x * 1024) {
        if (base + 1024 <= n) {   // full tile (only path for the bench shape)
            float4 p[4], q[4];
            int m[4];
            #pragma unroll
            for (int k = 0; k < 4; ++k) p[k] = pred4[base + 256 * k + i];
            #pragma unroll
            for (int k = 0; k < 4; ++k) q[k] = targ4[base + 256 * k + i];
            #pragma unroll
            for (int k = 0; k < 4; ++k) m[k] = mask[base + 256 * k + i];
            #pragma unroll
            for (int k = 0; k < 4; ++k) {
                bool valid = m[k] != 0;
                float mf = valid ? 1.0f : 0.0f;
                float c = ciou_one(p[k].x, p[k].y, p[k].z, p[k].w,
                                   q[k].x, q[k].y, q[k].z, q[k].w);
                out[1 + base + 256 * k + i] = c * mf;
                lsum += (1.0f - c) * mf;
                cnt += valid ? 1 : 0;
            }
        } else {                  // tail tile: per-element guard
            #pragma unroll
            for (int k = 0; k < 4; ++k) {
                int b = base + 256 * k + i;
                if (b < n) {
                    float4 p = pred4[b], q = targ4[b];
                    bool valid = mask[b] != 0;
                    float mf = valid ? 1.0f : 0.0f;
                    float c = ciou_one(p.x, p.y, p.z, p.w, q.x, q.y, q.z, q.w);
                    out[1 + b] = c * mf;
                    lsum += (1.0f - c) * mf;
                    cnt += valid ? 1 : 0;
                }
            }
        }
    }

    // block reduction: wave shfl, then cross-wave via LDS
    for (int off = 32; off > 0; off >>= 1) {
        lsum += __shfl_down(lsum, off);
        cnt  += __shfl_down(cnt, off);
    }
    __shared__ float sl[4];
    __shared__ int   sc[4];
    int w = i >> 6, lane = i & 63;
    if (lane == 0) { sl[w] = lsum; sc[w] = cnt; }
    __syncthreads();
    if (i == 0) {
        float L = fmaxf(sl[0] + sl[1] + sl[2] + sl[3], 0.0f);  // guard fp noise for u64 cast
        int   C = sc[0] + sc[1] + sc[2] + sc[3];
        atomicAdd(acc + 0, (unsigned long long)((double)L * FIXSCALE + 0.5));
        atomicAdd(acc + 1, (unsigned long long)C);
        __threadfence();                                   // partials visible before ticket
        unsigned long long tk = atomicAdd(acc + 2, 1ULL);
        if (tk == (unsigned long long)(gridDim.x - 1)) {   // last block: totals complete
            unsigned long long lv = atomicAdd(acc + 0, 0ULL);   // device-scope reads
            unsigned long long cv = atomicAdd(acc + 1, 0ULL);
            double loss = ((double)lv / FIXSCALE) / (double)(cv ? cv : 1ULL);
            out[0] = (float)loss;
        }
    }
}

extern "C" void kernel_launch(void* const* d_in, const int* in_sizes, int n_in,
                              void* d_out, int out_size, void* d_ws, size_t ws_size,
                              hipStream_t stream) {
    const float4* pred4 = (const float4*)d_in[0];
    const float4* targ4 = (const float4*)d_in[1];
    const int*    mask  = (const int*)d_in[2];
    float* out = (float*)d_out;
    int n = in_sizes[0] / 4;   // number of boxes

    unsigned long long* acc = (unsigned long long*)d_ws;
    hipMemsetAsync(d_ws, 0, 3 * sizeof(unsigned long long), stream);   // capturable stream op

    int nblocks = (n + 1023) / 1024;   // exact cover at 4 boxes/thread (4096 for bench)
    if (nblocks > 8192) nblocks = 8192;
    if (nblocks < 1) nblocks = 1;

    ciou_main<<<nblocks, 256, 0, stream>>>(pred4, targ4, mask, out, n, acc);
}

// Round 11
// 34.741 us; speedup vs baseline: 5.3652x; 5.3652x over previous
//
#include <hip/hip_runtime.h>

// DTYPES SETTLED (R6 post-mortem, executed-path evidence; R7-R10 passed on it):
//   boxes = fp32 (float*), mask = int32 (int*), out = fp32 (float*).
//
// STRUCTURE LOCKED (R10 post-mortem): two kernels, plain partial arrays.
//   - R10's fused same-line u64 atomics + threadfence: 4096 blocks serialize on one
//     cache line (~20ns/RMW x 12k ops) -> +208us. Never hot-spot a single line.
//   - R7(sunk loads) == R8(sched_barrier) == R9(LDS-DMA staging) == ~34us: perf is
//     invariant to load-concurrency structure -> ~5 TB/s mixed-stream service ceiling.
// R11 single variable: nontemporal (nt) map stores — stop write-allocating the 16.8MB
// output stream into L2/L3 so it doesn't compete with the 151MB input streams.

constexpr float EPSF      = 1e-9f;
constexpr float HALF_PI_F = 1.5707963267948966f;
constexpr float INV_PI2_4 = 0.40528473456935109f;   // 4 / pi^2

__device__ __forceinline__ float fast_rcp(float x) { return __builtin_amdgcn_rcpf(x); }

// minimax atan on [0,1], extended by atan(x) = pi/2 - atan(1/x); max err ~1e-6
// (validated within harness threshold by R1/R2/R4/R7/R8/R9/R10 passes)
__device__ __forceinline__ float fast_atan(float t) {
    float a = fabsf(t);
    bool big = a > 1.0f;
    float x = big ? fast_rcp(a) : a;
    float s = x * x;
    float p = -0.0117212f;
    p = fmaf(p, s, 0.05265332f);
    p = fmaf(p, s, -0.11643287f);
    p = fmaf(p, s, 0.19354346f);
    p = fmaf(p, s, -0.33262347f);
    p = fmaf(p, s, 0.99997726f);
    p = x * p;
    float r = big ? (HALF_PI_F - p) : p;
    return copysignf(r, t);
}

__device__ __forceinline__ float ciou_one(float x1a, float y1a, float x2a, float y2a,
                                          float x1b, float y1b, float x2b, float y2b) {
    float xmin = fmaxf(x1a, x1b), ymin = fmaxf(y1a, y1b);
    float xmax = fminf(x2a, x2b), ymax = fminf(y2a, y2b);
    float inter = fmaxf(xmax - xmin, 0.0f) * fmaxf(ymax - ymin, 0.0f);
    float wa = x2a - x1a, ha = y2a - y1a;
    float wb = x2b - x1b, hb = y2b - y1b;
    float uni = wa * ha + wb * hb - inter;
    float iou = inter * fast_rcp(uni + EPSF);
    float dx = (x1a + x2a) - (x1b + x2b);
    float dy = (y1a + y2a) - (y1b + y2b);
    float cd = 0.25f * (dx * dx + dy * dy);
    float cw = fmaxf(x2a, x2b) - fminf(x1a, x1b);
    float ch = fmaxf(y2a, y2b) - fminf(y1a, y1b);
    float diag = cw * cw + ch * ch + EPSF;
    // atan(wa/ha') - atan(wb/hb') == atan((wa*hb' - wb*ha')/(ha'*hb' + wa*wb));
    // both ratios >= 0, so branch-free exact, result in (-pi/2, pi/2)
    float ha_ = ha + EPSF, hb_ = hb + EPSF;
    float at = fast_atan((wa * hb_ - wb * ha_) * fast_rcp(ha_ * hb_ + wa * wb + EPSF));
    float v = INV_PI2_4 * at * at;
    float av = v * v * fast_rcp(v - iou + 1.0f + EPSF);   // alpha * v
    return iou - cd * fast_rcp(diag) - av;
}

// Main: 1024-box tile per block; thread i owns boxes base+i+256k, k=0..3 (lane-dense).
// Map stores are nontemporal (write-once stream, never re-read).
__global__ __launch_bounds__(256) void ciou_main(const float4* __restrict__ pred4,
                                                 const float4* __restrict__ targ4,
                                                 const int* __restrict__ mask,
                                                 float* __restrict__ out, int n,
                                                 float* __restrict__ part_loss,
                                                 float* __restrict__ part_cnt) {
    const int i = threadIdx.x;
    float lsum = 0.0f;
    int cnt = 0;

    for (int base = blockIdx.x * 1024; base < n; base += gridDim.x * 1024) {
        if (base + 1024 <= n) {   // full tile (only path for the bench shape)
            float4 p[4], q[4];
            int m[4];
            #pragma unroll
            for (int k = 0; k < 4; ++k) p[k] = pred4[base + 256 * k + i];
            #pragma unroll
            for (int k = 0; k < 4; ++k) q[k] = targ4[base + 256 * k + i];
            #pragma unroll
            for (int k = 0; k < 4; ++k) m[k] = mask[base + 256 * k + i];
            #pragma unroll
            for (int k = 0; k < 4; ++k) {
                bool valid = m[k] != 0;
                float mf = valid ? 1.0f : 0.0f;
                float c = ciou_one(p[k].x, p[k].y, p[k].z, p[k].w,
                                   q[k].x, q[k].y, q[k].z, q[k].w);
                __builtin_nontemporal_store(c * mf, &out[1 + base + 256 * k + i]);
                lsum += (1.0f - c) * mf;
                cnt += valid ? 1 : 0;
            }
        } else {                  // tail tile: per-element guard
            #pragma unroll
            for (int k = 0; k < 4; ++k) {
                int b = base + 256 * k + i;
                if (b < n) {
                    float4 p = pred4[b], q = targ4[b];
                    bool valid = mask[b] != 0;
                    float mf = valid ? 1.0f : 0.0f;
                    float c = ciou_one(p.x, p.y, p.z, p.w, q.x, q.y, q.z, q.w);
                    __builtin_nontemporal_store(c * mf, &out[1 + b]);
                    lsum += (1.0f - c) * mf;
                    cnt += valid ? 1 : 0;
                }
            }
        }
    }

    // block reduction: wave shfl, then cross-wave via LDS
    for (int off = 32; off > 0; off >>= 1) {
        lsum += __shfl_down(lsum, off);
        cnt  += __shfl_down(cnt, off);
    }
    __shared__ float sl[4];
    __shared__ int   sc[4];
    int w = i >> 6, lane = i & 63;
    if (lane == 0) { sl[w] = lsum; sc[w] = cnt; }
    __syncthreads();
    if (i == 0) {
        part_loss[blockIdx.x] = sl[0] + sl[1] + sl[2] + sl[3];
        part_cnt[blockIdx.x]  = (float)(sc[0] + sc[1] + sc[2] + sc[3]);
    }
}

// Finalize: deterministic fixed-order double reduction; writes fp32 scalar to out[0].
__global__ __launch_bounds__(1024) void finalize_kernel(const float* __restrict__ part_loss,
                                                        const float* __restrict__ part_cnt,
                                                        float* __restrict__ out, int nb) {
    __shared__ double sl[1024], sc[1024];
    const int t = threadIdx.x;
    double l = 0.0, c = 0.0;
    for (int j = t; j < nb; j += 1024) {
        l += (double)part_loss[j];
        c += (double)part_cnt[j];
    }
    sl[t] = l; sc[t] = c;
    __syncthreads();
    for (int s = 512; s > 0; s >>= 1) {
        if (t < s) { sl[t] += sl[t + s]; sc[t] += sc[t + s]; }
        __syncthreads();
    }
    if (t == 0) out[0] = (float)(sl[0] / fmax(sc[0], 1.0));
}

extern "C" void kernel_launch(void* const* d_in, const int* in_sizes, int n_in,
                              void* d_out, int out_size, void* d_ws, size_t ws_size,
                              hipStream_t stream) {
    const float4* pred4 = (const float4*)d_in[0];
    const float4* targ4 = (const float4*)d_in[1];
    const int*    mask  = (const int*)d_in[2];
    float* out = (float*)d_out;
    int n = in_sizes[0] / 4;   // number of boxes

    int nblocks = (n + 1023) / 1024;                     // exact cover at 4 boxes/thread
    int ws_cap = (int)(ws_size / (2 * sizeof(float)));   // partials must fit in d_ws
    if (nblocks > ws_cap) nblocks = ws_cap;
    if (nblocks > 8192) nblocks = 8192;
    if (nblocks < 1) nblocks = 1;
    float* part_loss = (float*)d_ws;
    float* part_cnt  = part_loss + nblocks;

    ciou_main<<<nblocks, 256, 0, stream>>>(pred4, targ4, mask, out, n, part_loss, part_cnt);
    finalize_kernel<<<1, 1024, 0, stream>>>(part_loss, part_cnt, out, nblocks);
}

// Round 12
// 33.762 us; speedup vs baseline: 5.5208x; 1.0290x over previous
//
#include <hip/hip_runtime.h>

// DTYPES SETTLED (R6 post-mortem, executed-path evidence; R7-R11 passed on it):
//   boxes = fp32 (float*), mask = int32 (int*), out = fp32 (float*).
//
// FINAL STRUCTURE (roofline-justified):
//   - Obligatory traffic 167.8 MB (151 read + 16.8 write); best bench 33.9us
//     = 4.95 TB/s e2e; main dispatch ~5.7 TB/s = ~90% of 6.3 TB/s copy ceiling.
//   - Concurrency-invariant: R7(sunk loads) == R8(sched_barrier) == R9(LDS-DMA).
//   - R10: single-line atomic fusion +208us (cross-XCD line ping-pong). Two kernels.
//   - R11: nontemporal stores -> WRITE_SIZE +11% (lost L2 write-merge). Reverted.

constexpr float EPSF      = 1e-9f;
constexpr float HALF_PI_F = 1.5707963267948966f;
constexpr float INV_PI2_4 = 0.40528473456935109f;   // 4 / pi^2

__device__ __forceinline__ float fast_rcp(float x) { return __builtin_amdgcn_rcpf(x); }

// minimax atan on [0,1], extended by atan(x) = pi/2 - atan(1/x); max err ~1e-6
// (validated within harness threshold by R1/R2/R4/R7-R11 passes)
__device__ __forceinline__ float fast_atan(float t) {
    float a = fabsf(t);
    bool big = a > 1.0f;
    float x = big ? fast_rcp(a) : a;
    float s = x * x;
    float p = -0.0117212f;
    p = fmaf(p, s, 0.05265332f);
    p = fmaf(p, s, -0.11643287f);
    p = fmaf(p, s, 0.19354346f);
    p = fmaf(p, s, -0.33262347f);
    p = fmaf(p, s, 0.99997726f);
    p = x * p;
    float r = big ? (HALF_PI_F - p) : p;
    return copysignf(r, t);
}

__device__ __forceinline__ float ciou_one(float x1a, float y1a, float x2a, float y2a,
                                          float x1b, float y1b, float x2b, float y2b) {
    float xmin = fmaxf(x1a, x1b), ymin = fmaxf(y1a, y1b);
    float xmax = fminf(x2a, x2b), ymax = fminf(y2a, y2b);
    float inter = fmaxf(xmax - xmin, 0.0f) * fmaxf(ymax - ymin, 0.0f);
    float wa = x2a - x1a, ha = y2a - y1a;
    float wb = x2b - x1b, hb = y2b - y1b;
    float uni = wa * ha + wb * hb - inter;
    float iou = inter * fast_rcp(uni + EPSF);
    float dx = (x1a + x2a) - (x1b + x2b);
    float dy = (y1a + y2a) - (y1b + y2b);
    float cd = 0.25f * (dx * dx + dy * dy);
    float cw = fmaxf(x2a, x2b) - fminf(x1a, x1b);
    float ch = fmaxf(y2a, y2b) - fminf(y1a, y1b);
    float diag = cw * cw + ch * ch + EPSF;
    // atan(wa/ha') - atan(wb/hb') == atan((wa*hb' - wb*ha')/(ha'*hb' + wa*wb));
    // both ratios >= 0, so branch-free exact, result in (-pi/2, pi/2)
    float ha_ = ha + EPSF, hb_ = hb + EPSF;
    float at = fast_atan((wa * hb_ - wb * ha_) * fast_rcp(ha_ * hb_ + wa * wb + EPSF));
    float v = INV_PI2_4 * at * at;
    float av = v * v * fast_rcp(v - iou + 1.0f + EPSF);   // alpha * v
    return iou - cd * fast_rcp(diag) - av;
}

// Main: 1024-box tile per block; thread i owns boxes base+i+256k, k=0..3.
// Every load/store instruction is lane-dense (float4: 1KiB/wave).
__global__ __launch_bounds__(256) void ciou_main(const float4* __restrict__ pred4,
                                                 const float4* __restrict__ targ4,
                                                 const int* __restrict__ mask,
                                                 float* __restrict__ out, int n,
                                                 float* __restrict__ part_loss,
                                                 float* __restrict__ part_cnt) {
    const int i = threadIdx.x;
    float lsum = 0.0f;
    int cnt = 0;

    for (int base = blockIdx.x * 1024; base < n; base += gridDim.x * 1024) {
        if (base + 1024 <= n) {   // full tile (only path for the bench shape)
            float4 p[4], q[4];
            int m[4];
            #pragma unroll
            for (int k = 0; k < 4; ++k) p[k] = pred4[base + 256 * k + i];
            #pragma unroll
            for (int k = 0; k < 4; ++k) q[k] = targ4[base + 256 * k + i];
            #pragma unroll
            for (int k = 0; k < 4; ++k) m[k] = mask[base + 256 * k + i];
            #pragma unroll
            for (int k = 0; k < 4; ++k) {
                bool valid = m[k] != 0;
                float mf = valid ? 1.0f : 0.0f;
                float c = ciou_one(p[k].x, p[k].y, p[k].z, p[k].w,
                                   q[k].x, q[k].y, q[k].z, q[k].w);
                out[1 + base + 256 * k + i] = c * mf;
                lsum += (1.0f - c) * mf;
                cnt += valid ? 1 : 0;
            }
        } else {                  // tail tile: per-element guard
            #pragma unroll
            for (int k = 0; k < 4; ++k) {
                int b = base + 256 * k + i;
                if (b < n) {
                    float4 p = pred4[b], q = targ4[b];
                    bool valid = mask[b] != 0;
                    float mf = valid ? 1.0f : 0.0f;
                    float c = ciou_one(p.x, p.y, p.z, p.w, q.x, q.y, q.z, q.w);
                    out[1 + b] = c * mf;
                    lsum += (1.0f - c) * mf;
                    cnt += valid ? 1 : 0;
                }
            }
        }
    }

    // block reduction: wave shfl, then cross-wave via LDS
    for (int off = 32; off > 0; off >>= 1) {
        lsum += __shfl_down(lsum, off);
        cnt  += __shfl_down(cnt, off);
    }
    __shared__ float sl[4];
    __shared__ int   sc[4];
    int w = i >> 6, lane = i & 63;
    if (lane == 0) { sl[w] = lsum; sc[w] = cnt; }
    __syncthreads();
    if (i == 0) {
        part_loss[blockIdx.x] = sl[0] + sl[1] + sl[2] + sl[3];
        part_cnt[blockIdx.x]  = (float)(sc[0] + sc[1] + sc[2] + sc[3]);
    }
}

// Finalize: deterministic fixed-order double reduction; writes fp32 scalar to out[0].
__global__ __launch_bounds__(1024) void finalize_kernel(const float* __restrict__ part_loss,
                                                        const float* __restrict__ part_cnt,
                                                        float* __restrict__ out, int nb) {
    __shared__ double sl[1024], sc[1024];
    const int t = threadIdx.x;
    double l = 0.0, c = 0.0;
    for (int j = t; j < nb; j += 1024) {
        l += (double)part_loss[j];
        c += (double)part_cnt[j];
    }
    sl[t] = l; sc[t] = c;
    __syncthreads();
    for (int s = 512; s > 0; s >>= 1) {
        if (t < s) { sl[t] += sl[t + s]; sc[t] += sc[t + s]; }
        __syncthreads();
    }
    if (t == 0) out[0] = (float)(sl[0] / fmax(sc[0], 1.0));
}

extern "C" void kernel_launch(void* const* d_in, const int* in_sizes, int n_in,
                              void* d_out, int out_size, void* d_ws, size_t ws_size,
                              hipStream_t stream) {
    const float4* pred4 = (const float4*)d_in[0];
    const float4* targ4 = (const float4*)d_in[1];
    const int*    mask  = (const int*)d_in[2];
    float* out = (float*)d_out;
    int n = in_sizes[0] / 4;   // number of boxes

    int nblocks = (n + 1023) / 1024;                     // exact cover at 4 boxes/thread
    int ws_cap = (int)(ws_size / (2 * sizeof(float)));   // partials must fit in d_ws
    if (nblocks > ws_cap) nblocks = ws_cap;
    if (nblocks > 8192) nblocks = 8192;
    if (nblocks < 1) nblocks = 1;
    float* part_loss = (float*)d_ws;
    float* part_cnt  = part_loss + nblocks;

    ciou_main<<<nblocks, 256, 0, stream>>>(pred4, targ4, mask, out, n, part_loss, part_cnt);
    finalize_kernel<<<1, 1024, 0, stream>>>(part_loss, part_cnt, out, nblocks);
}